// Round 5
// baseline (589.376 us; speedup 1.0000x reference)
//
#include <hip/hip_runtime.h>
#include <math.h>

// ---------------------------------------------------------------------------
// I2HOFI forward. B=8, 13 ROI graphs x 392 nodes (intra) / 392 x 13 (inter),
// feature 256. bf16 MFMA GEMMs: B (weights) resident in VGPRs (forced via
// __launch_bounds__), A streamed with explicit 2-deep double buffer, waves
// cover distinct col-groups over shared rows (A hits L1).
// Node row layout: row = (b*13 + r)*392 + c.
// x2 rows padded per (branch,b) segment: seg*5120 + within (within < 5096).
// ---------------------------------------------------------------------------

typedef __attribute__((ext_vector_type(8))) short bf16x8;
typedef __attribute__((ext_vector_type(4))) float f32x4;
typedef __attribute__((ext_vector_type(4))) short short4v;

#define MFMA16x32(a, b, c) __builtin_amdgcn_mfma_f32_16x16x32_bf16((a), (b), (c), 0, 0, 0)

__device__ __forceinline__ float sigmoidf_(float x) { return 1.0f / (1.0f + expf(-x)); }
__device__ __forceinline__ float leakyf_(float x) { return x >= 0.0f ? x : 0.2f * x; }
__device__ __forceinline__ float eluf_(float x) { return x > 0.0f ? x : expm1f(x); }
__device__ __forceinline__ short f2bf(float f) {
  unsigned u = __builtin_bit_cast(unsigned, f);
  unsigned r = u + 0x7fffu + ((u >> 16) & 1u);
  return (short)(r >> 16);
}
__device__ __forceinline__ float bf2f(short s) {
  unsigned u = ((unsigned)(unsigned short)s) << 16;
  return __builtin_bit_cast(float, u);
}
__device__ __forceinline__ f32x4 fzero4() {
  f32x4 z;
  #pragma unroll
  for (int i = 0; i < 4; ++i) z[i] = 0.0f;
  return z;
}

// --------------------------------------------------------------------------
// K0: composed resize weight tables. wtab[roi][axis][o][ib], 13*2*7*7.
// --------------------------------------------------------------------------
__global__ void wtab_k(float* __restrict__ wtab) {
  const int RX[12] = {0,14,28, 0,14,28, 0,14,28, 0, 0, 0};
  const int RY[12] = {0, 0, 0,14,14,14,28,28,28, 0,21, 0};
  const int RW[12] = {14,14,14,14,14,14,14,14,14,42,42,42};
  const int RH[12] = {14,14,14,14,14,14,14,14,14,21,21,42};
  for (int e = threadIdx.x; e < 13 * 2 * 49; e += blockDim.x) {
    const int roi = e / 98;
    const int rest = e % 98;
    const int axis = rest / 49;
    const int o = (rest % 49) / 7;
    const int ib = rest % 7;
    float wout;
    if (roi == 12) {
      wout = (o == ib) ? 1.0f : 0.0f;
    } else {
      const int start = axis ? RX[roi] : RY[roi];
      const int len = axis ? RW[roi] : RH[roi];
      const float s = (float)len / 7.0f;
      const float oc = (o + 0.5f) * s - 0.5f;
      float wsum = 0.0f, dot = 0.0f;
      for (int j = 0; j < len; ++j) {
        float w = 1.0f - fabsf((float)j - oc) / s;
        if (w <= 0.0f) continue;
        wsum += w;
        const float ic = ((float)(start + j) + 0.5f) / 6.0f - 0.5f;
        const float fl = floorf(ic);
        const int ia = (int)fl;
        const float fr = ic - fl;
        int c0 = ia;     if (c0 < 0) c0 = 0; if (c0 > 6) c0 = 6;
        int c1 = ia + 1; if (c1 < 0) c1 = 0; if (c1 > 6) c1 = 6;
        float u = 0.0f;
        if (c0 == ib) u += 1.0f - fr;
        if (c1 == ib) u += fr;
        dot += w * u;
      }
      wout = dot / wsum;
    }
    wtab[e] = wout;
  }
}

// --------------------------------------------------------------------------
// Weight transpose + bf16 convert: dst[n][k] from src[k][n] fp32.
// --------------------------------------------------------------------------
__global__ void wcvt_k(const float* __restrict__ src, short* __restrict__ hi,
                       int K, int N) {
  const int idx = blockIdx.x * 256 + threadIdx.x;
  if (idx >= K * N) return;
  const int k = idx / N, n = idx % N;
  hi[(size_t)n * K + k] = f2bf(src[idx]);
}

// --------------------------------------------------------------------------
// was = gat_k @ a_self, wan = gat_k @ a_neigh (fp32). Wave per row.
// --------------------------------------------------------------------------
__global__ void wvec_k(const float* __restrict__ Wk, const float* __restrict__ as,
                       const float* __restrict__ an, float* __restrict__ was,
                       float* __restrict__ wan) {
  const int w = threadIdx.x >> 6, l = threadIdx.x & 63;
  const int row = blockIdx.x * 4 + w;
  const float* p = Wk + (size_t)row * 256;
  float s = 0.0f, t = 0.0f;
  #pragma unroll
  for (int j = 0; j < 4; ++j) {
    const int o = l + j * 64;
    const float v = p[o];
    s = fmaf(v, as[o], s);
    t = fmaf(v, an[o], t);
  }
  #pragma unroll
  for (int off = 32; off; off >>= 1) { s += __shfl_down(s, off); t += __shfl_down(t, off); }
  if (l == 0) { was[row] = s; wan[row] = t; }
}

// --------------------------------------------------------------------------
// K1: nodes (bf16) via separable 49x49 resize contraction.
// --------------------------------------------------------------------------
__global__ __launch_bounds__(256) void nodes_k(const float* __restrict__ base,
                                               const float* __restrict__ wtab,
                                               short* __restrict__ nodes) {
  const int blk = blockIdx.x;
  const int chunk = blk & 7;
  const int br = blk >> 3;
  const int r = br % 13;
  const int b = br / 13;
  const int f = threadIdx.x;
  __shared__ float W49[49][50];
  const float* wv = wtab + (r * 2 + 0) * 49;
  const float* wh = wtab + (r * 2 + 1) * 49;
  for (int e = f; e < 2401; e += 256) {
    const int o = e / 49, in = e % 49;
    W49[o][in] = wv[(o / 7) * 7 + in / 7] * wh[(o % 7) * 7 + in % 7];
  }
  __syncthreads();
  float bv[49];
  const float* bp = base + (size_t)b * 49 * 2048 + chunk * 256 + f;
  #pragma unroll
  for (int in = 0; in < 49; ++in) bv[in] = bp[(size_t)in * 2048];
  const size_t obase = ((size_t)(b * 13 + r) * 392 + chunk * 49) * 256 + f;
  for (int o = 0; o < 49; ++o) {
    float acc = 0.0f;
    #pragma unroll
    for (int in = 0; in < 49; ++in) acc = fmaf(W49[o][in], bv[in], acc);
    nodes[obase + (size_t)o * 256] = f2bf(acc);
  }
}

// --------------------------------------------------------------------------
// Register-B GEMM: C[M][256] = A[M][256] @ W (WT layout [N=256][K=256]).
// 4 waves x 16 cols (distinct col-groups, shared rows -> A from L1).
// Explicit 2-deep A double-buffer, 2-way ks-split accumulators.
// grid (ceil(M/128), 4). EPI 0: plain bf16. EPI 1: sigmoid(acc+bias).
// --------------------------------------------------------------------------
template <int EPI>
__global__ __launch_bounds__(256, 4) void gemm_rb_k(const short* __restrict__ A,
    const short* __restrict__ WT, const float* __restrict__ bias,
    short* __restrict__ C, int M) {
  const int tid = threadIdx.x;
  const int w = tid >> 6, l = tid & 63;
  const int lr = l & 15, kb = l >> 4;
  const int n0 = blockIdx.y * 64 + w * 16;
  bf16x8 vb[8];
  #pragma unroll
  for (int ks = 0; ks < 8; ++ks)
    vb[ks] = *(const bf16x8*)(WT + (size_t)(n0 + lr) * 256 + ks * 32 + kb * 8);
  float bs = 0.0f;
  if (EPI == 1) bs = bias[n0 + lr];
  const int mstart = blockIdx.x * 128;
  const int mend = (mstart + 128 < M) ? (mstart + 128) : M;
  const short* abase = A + (size_t)lr * 256 + kb * 8;
  bf16x8 vaA[8], vaB[8];
  #pragma unroll
  for (int ks = 0; ks < 8; ++ks)
    vaA[ks] = *(const bf16x8*)(abase + (size_t)mstart * 256 + ks * 32);
  for (int m0 = mstart; m0 < mend; m0 += 32) {
    const bool hasB = (m0 + 16 < mend);
    if (hasB) {
      #pragma unroll
      for (int ks = 0; ks < 8; ++ks)
        vaB[ks] = *(const bf16x8*)(abase + (size_t)(m0 + 16) * 256 + ks * 32);
    }
    {
      f32x4 a0 = fzero4(), a1 = fzero4();
      #pragma unroll
      for (int ks = 0; ks < 8; ks += 2) {
        a0 = MFMA16x32(vaA[ks], vb[ks], a0);
        a1 = MFMA16x32(vaA[ks + 1], vb[ks + 1], a1);
      }
      #pragma unroll
      for (int r = 0; r < 4; ++r) {
        float o = a0[r] + a1[r];
        if (EPI == 1) o = sigmoidf_(o + bs);
        C[(size_t)(m0 + kb * 4 + r) * 256 + n0 + lr] = f2bf(o);
      }
    }
    if (hasB) {
      if (m0 + 32 < mend) {
        #pragma unroll
        for (int ks = 0; ks < 8; ++ks)
          vaA[ks] = *(const bf16x8*)(abase + (size_t)(m0 + 32) * 256 + ks * 32);
      }
      f32x4 a0 = fzero4(), a1 = fzero4();
      #pragma unroll
      for (int ks = 0; ks < 8; ks += 2) {
        a0 = MFMA16x32(vaB[ks], vb[ks], a0);
        a1 = MFMA16x32(vaB[ks + 1], vb[ks + 1], a1);
      }
      #pragma unroll
      for (int r = 0; r < 4; ++r) {
        float o = a0[r] + a1[r];
        if (EPI == 1) o = sigmoidf_(o + bs);
        C[(size_t)(m0 + 16 + kb * 4 + r) * 256 + n0 + lr] = f2bf(o);
      }
    }
  }
}

// --------------------------------------------------------------------------
// Transpose xp[g][392][256] -> xpT[g][256][416] (cols 392..415 zero).
// 64x64 tiles, LDS stride 66 (bank-conflict-free both ways).
// --------------------------------------------------------------------------
__global__ __launch_bounds__(256) void transpose_k(const short* __restrict__ xp,
                                                   short* __restrict__ xpT) {
  const int m0 = blockIdx.x * 64;
  const int f0 = blockIdx.y * 64;
  const int g = blockIdx.z;
  const int tid = threadIdx.x;
  __shared__ short tile[64][66];
  const int c = tid & 63;
  const int r4 = tid >> 6;
  #pragma unroll
  for (int p = 0; p < 16; ++p) {
    const int row = p * 4 + r4;
    const int m = m0 + row;
    tile[row][c] = (m < 392) ? xp[((size_t)g * 392 + m) * 256 + f0 + c] : (short)0;
  }
  __syncthreads();
  #pragma unroll
  for (int p = 0; p < 16; ++p) {
    const int fr = p * 4 + r4;
    if (m0 + c < 416)
      xpT[((size_t)g * 256 + f0 + fr) * 416 + m0 + c] = tile[c][fr];
  }
}

// --------------------------------------------------------------------------
// Graph feature sums of m (bf16 in, fp32 out).
// --------------------------------------------------------------------------
__global__ void sums_intra_k(const short* __restrict__ m, float* __restrict__ S) {
  const int g = blockIdx.x;
  const int f = threadIdx.x;
  const short* p = m + (size_t)g * 392 * 256 + f;
  float a0 = 0.0f, a1 = 0.0f, a2 = 0.0f, a3 = 0.0f;
  for (int c = 0; c < 392; c += 4) {
    a0 += bf2f(p[(size_t)(c + 0) * 256]);
    a1 += bf2f(p[(size_t)(c + 1) * 256]);
    a2 += bf2f(p[(size_t)(c + 2) * 256]);
    a3 += bf2f(p[(size_t)(c + 3) * 256]);
  }
  S[(size_t)g * 256 + f] = (a0 + a1) + (a2 + a3);
}

__global__ void sums_inter_k(const short* __restrict__ m, float* __restrict__ S) {
  const int g = blockIdx.x;
  const int b = g / 392, c = g % 392;
  const int f = threadIdx.x;
  const short* p = m + ((size_t)(b * 13) * 392 + c) * 256 + f;
  float acc = 0.0f;
  #pragma unroll
  for (int r = 0; r < 13; ++r) acc += bf2f(p[(size_t)r * 392 * 256]);
  S[(size_t)g * 256 + f] = acc;
}

// --------------------------------------------------------------------------
// h = 0.9*(S_g + m)/(n+1) + 0.1*m + x  (APPNP + residual), bf16x8 vectorized.
// --------------------------------------------------------------------------
__global__ void h_intra_v(const short* __restrict__ nodes, const short* __restrict__ m,
                          const float* __restrict__ S, short* __restrict__ h) {
  const size_t e0 = ((size_t)blockIdx.x * 256 + threadIdx.x) * 8;
  const int row = (int)(e0 >> 8);
  const int f0 = (int)(e0 & 255);
  const int g = row / 392;
  const bf16x8 mv8 = *(const bf16x8*)(m + e0);
  const bf16x8 nv8 = *(const bf16x8*)(nodes + e0);
  const float* Sp = S + (size_t)g * 256 + f0;
  bf16x8 o;
  #pragma unroll
  for (int i = 0; i < 8; ++i) {
    const float mv = bf2f(mv8[i]);
    o[i] = f2bf(0.9f * (Sp[i] + mv) * (1.0f / 393.0f) + 0.1f * mv + bf2f(nv8[i]));
  }
  *(bf16x8*)(h + e0) = o;
}

__global__ void h_inter_v(const short* __restrict__ nodes, const short* __restrict__ m,
                          const float* __restrict__ S, short* __restrict__ h) {
  const size_t e0 = ((size_t)blockIdx.x * 256 + threadIdx.x) * 8;
  const int row = (int)(e0 >> 8);
  const int f0 = (int)(e0 & 255);
  const int b = row / 5096;
  const int c = row % 392;
  const int g = b * 392 + c;
  const bf16x8 mv8 = *(const bf16x8*)(m + e0);
  const bf16x8 nv8 = *(const bf16x8*)(nodes + e0);
  const float* Sp = S + (size_t)g * 256 + f0;
  bf16x8 o;
  #pragma unroll
  for (int i = 0; i < 8; ++i) {
    const float mv = bf2f(mv8[i]);
    o[i] = f2bf(0.9f * (Sp[i] + mv) * (1.0f / 14.0f) + 0.1f * mv + bf2f(nv8[i]));
  }
  *(bf16x8*)(h + e0) = o;
}

// --------------------------------------------------------------------------
// Attention scalars from h: s = h . was, t = h . wan  (s = xp.a identity).
// One wave per row, coalesced short4 loads.
// --------------------------------------------------------------------------
__global__ void st_h_k(const short* __restrict__ h, const float* __restrict__ was,
                       const float* __restrict__ wan, float* __restrict__ sb,
                       float* __restrict__ tb, int M) {
  const int row = (int)(((size_t)blockIdx.x * blockDim.x + threadIdx.x) >> 6);
  const int lane = threadIdx.x & 63;
  if (row >= M) return;
  const short4v v = *(const short4v*)(h + (size_t)row * 256 + lane * 4);
  float s = 0.0f, t = 0.0f;
  #pragma unroll
  for (int j = 0; j < 4; ++j) {
    const float x = bf2f(v[j]);
    s = fmaf(x, was[lane * 4 + j], s);
    t = fmaf(x, wan[lane * 4 + j], t);
  }
  #pragma unroll
  for (int off = 32; off; off >>= 1) { s += __shfl_down(s, off); t += __shfl_down(t, off); }
  if (lane == 0) { sb[row] = s; tb[row] = t; }
}

// --------------------------------------------------------------------------
// Intra E matrix (bf16, [g][512][416] stride; rows 0..447 written) + 1/denom.
// --------------------------------------------------------------------------
__global__ __launch_bounds__(256) void attn_e_k(const float* __restrict__ sb,
    const float* __restrict__ tb, short* __restrict__ E, float* __restrict__ dinv) {
  const int g = blockIdx.y;
  const int n0 = blockIdx.x * 32;
  const int tid = threadIdx.x;
  __shared__ float t_s[392];
  __shared__ float red[256];
  for (int i = tid; i < 392; i += 256) t_s[i] = tb[(size_t)g * 392 + i];
  __syncthreads();
  float lm = -1e30f;
  for (int i = tid; i < 392; i += 256) lm = fmaxf(lm, t_s[i]);
  red[tid] = lm;
  __syncthreads();
  for (int off = 128; off; off >>= 1) {
    if (tid < off) red[tid] = fmaxf(red[tid], red[tid + off]);
    __syncthreads();
  }
  const float tmax = red[0];
  const int n = n0 + (tid >> 3);
  const int ml = tid & 7;
  const bool nv = (n < 392);
  const float sv = nv ? sb[(size_t)g * 392 + n] : 0.0f;
  const float lt = leakyf_(sv + tmax);
  float d = 0.0f;
  short* erow = E + ((size_t)g * 512 + n) * 416;
  for (int m = ml; m < 416; m += 8) {
    float e = 0.0f;
    if (nv && m < 392) e = expf(leakyf_(sv + t_s[m]) - lt);
    erow[m] = f2bf(e);
    d += e;
  }
  d += __shfl_xor(d, 1); d += __shfl_xor(d, 2); d += __shfl_xor(d, 4);
  if (nv && ml == 0) dinv[(size_t)g * 392 + n] = 1.0f / d;
}

// --------------------------------------------------------------------------
// Intra PV: out = E @ xp; register-B = xpT fragments (wave owns 16 f-cols),
// stream E row-groups. grid (4 fb, 2 rh(256 rows), G).
// --------------------------------------------------------------------------
__global__ __launch_bounds__(256, 4) void pv_rb_k(const short* __restrict__ E,
    const short* __restrict__ xpT, const float* __restrict__ dinv,
    const float* __restrict__ bias, const short* __restrict__ h,
    short* __restrict__ x2) {
  const int g = blockIdx.z;
  const int rh = blockIdx.y;
  const int tid = threadIdx.x;
  const int w = tid >> 6, l = tid & 63;
  const int lr = l & 15, kb = l >> 4;
  const int col = blockIdx.x * 64 + w * 16 + lr;
  bf16x8 vb[13];
  #pragma unroll
  for (int ks = 0; ks < 13; ++ks)
    vb[ks] = *(const bf16x8*)(xpT + ((size_t)g * 256 + col) * 416 + ks * 32 + kb * 8);
  const float bv = bias[col];
  const int bb = g / 13, rr = g % 13;
  const short* ebase = E + ((size_t)g * 512 + rh * 256 + lr) * 416 + kb * 8;
  for (int j = 0; j < 16; ++j) {
    bf16x8 va[13];
    const short* ap = ebase + (size_t)j * 16 * 416;
    #pragma unroll
    for (int ks = 0; ks < 13; ++ks) va[ks] = *(const bf16x8*)(ap + ks * 32);
    f32x4 acc = fzero4();
    #pragma unroll
    for (int ks = 0; ks < 13; ++ks) acc = MFMA16x32(va[ks], vb[ks], acc);
    #pragma unroll
    for (int r = 0; r < 4; ++r) {
      const int orow = rh * 256 + j * 16 + kb * 4 + r;
      if (orow < 392) {
        const size_t grow = (size_t)g * 392 + orow;
        const float o = acc[r] * dinv[grow];
        const float val = eluf_(o + bv) + bf2f(h[grow * 256 + col]);
        x2[((size_t)bb * 5120 + rr * 392 + orow) * 256 + col] = f2bf(val);
      }
    }
  }
}

// --------------------------------------------------------------------------
// Inter attention: 13-node graphs, one block per (b,c).
// --------------------------------------------------------------------------
__global__ __launch_bounds__(256) void attn_inter_k(const short* __restrict__ xp,
    const float* __restrict__ sb, const float* __restrict__ tb,
    const short* __restrict__ h, const float* __restrict__ bias,
    short* __restrict__ x2, int B) {
  const int g = blockIdx.x;
  const int b = g / 392, c = g % 392;
  const int tid = threadIdx.x;
  __shared__ float xps[13][256];
  __shared__ float e_s[13][14];
  __shared__ float sv[13], tv[13], denom[13];
  __shared__ float tmax_s;
  for (int lin = tid; lin < 13 * 256; lin += 256) {
    const int r = lin >> 8, f = lin & 255;
    xps[r][f] = bf2f(xp[((size_t)(b * 13 + r) * 392 + c) * 256 + f]);
  }
  if (tid < 13) {
    const size_t row = (size_t)(b * 13 + tid) * 392 + c;
    sv[tid] = sb[row];
    tv[tid] = tb[row];
  }
  __syncthreads();
  if (tid == 0) {
    float mx = tv[0];
    for (int r = 1; r < 13; ++r) mx = fmaxf(mx, tv[r]);
    tmax_s = mx;
  }
  __syncthreads();
  if (tid < 169) {
    const int n = tid / 13, mm = tid % 13;
    e_s[n][mm] = expf(leakyf_(sv[n] + tv[mm]) - leakyf_(sv[n] + tmax_s));
  }
  __syncthreads();
  if (tid < 13) {
    float d = 0.0f;
    for (int mm = 0; mm < 13; ++mm) d += e_s[tid][mm];
    denom[tid] = d;
  }
  __syncthreads();
  const int f = tid;
  for (int n = 0; n < 13; ++n) {
    float acc = 0.0f;
    #pragma unroll
    for (int mm = 0; mm < 13; ++mm) acc = fmaf(e_s[n][mm], xps[mm][f], acc);
    const float o = acc / denom[n];
    const size_t hbase = ((size_t)(b * 13 + n) * 392 + c) * 256 + f;
    x2[(((size_t)(B + b)) * 5120 + (size_t)n * 392 + c) * 256 + f] =
        f2bf(eluf_(o + bias[f]) + bf2f(h[hbase]));
  }
}

// --------------------------------------------------------------------------
// Pool (register-B, forced resident): xf[b] += sum_rows sigmoid(gate)*(feat).
// Wave owns 16 cols of BOTH Wf and Wa; 2-deep A double buffer; 2-way acc
// split per matrix. grid (MP/512, 8).
// --------------------------------------------------------------------------
__global__ __launch_bounds__(256, 3) void pool_rb_k(const short* __restrict__ x2,
    const short* __restrict__ pfT, const float* __restrict__ bf_,
    const short* __restrict__ paT, const float* __restrict__ ba_,
    float* __restrict__ xf, int B) {
  const int tid = threadIdx.x;
  const int w = tid >> 6, l = tid & 63;
  const int lr = l & 15, kb = l >> 4;
  const int col = blockIdx.y * 64 + w * 16 + lr;
  bf16x8 vbf[8], vba[8];
  #pragma unroll
  for (int ks = 0; ks < 8; ++ks) {
    vbf[ks] = *(const bf16x8*)(pfT + (size_t)col * 256 + ks * 32 + kb * 8);
    vba[ks] = *(const bf16x8*)(paT + (size_t)col * 256 + ks * 32 + kb * 8);
  }
  const float bfv = bf_[col], bav = ba_[col];
  const int seg = blockIdx.x / 10;             // 10 blocks of 512 rows / segment
  const int base = (blockIdx.x % 10) * 512;
  const int b = seg % B;
  const short* abase = x2 + ((size_t)seg * 5120 + base + lr) * 256 + kb * 8;
  float colsum = 0.0f;
  bf16x8 vaA[8], vaB[8];
  #pragma unroll
  for (int ks = 0; ks < 8; ++ks) vaA[ks] = *(const bf16x8*)(abase + (size_t)ks * 32);
  for (int mo = 0; mo < 512; mo += 32) {
    #pragma unroll
    for (int ks = 0; ks < 8; ++ks)
      vaB[ks] = *(const bf16x8*)(abase + (size_t)(mo + 16) * 256 + ks * 32);
    {
      f32x4 f0 = fzero4(), f1 = fzero4(), g0 = fzero4(), g1 = fzero4();
      #pragma unroll
      for (int ks = 0; ks < 8; ks += 2) {
        f0 = MFMA16x32(vaA[ks], vbf[ks], f0);
        g0 = MFMA16x32(vaA[ks], vba[ks], g0);
        f1 = MFMA16x32(vaA[ks + 1], vbf[ks + 1], f1);
        g1 = MFMA16x32(vaA[ks + 1], vba[ks + 1], g1);
      }
      const int rin = base + mo + kb * 4;
      #pragma unroll
      for (int r = 0; r < 4; ++r)
        if (rin + r < 5096)
          colsum += sigmoidf_(g0[r] + g1[r] + bav) * (f0[r] + f1[r] + bfv);
    }
    if (mo + 32 < 512) {
      #pragma unroll
      for (int ks = 0; ks < 8; ++ks)
        vaA[ks] = *(const bf16x8*)(abase + (size_t)(mo + 32) * 256 + ks * 32);
    }
    {
      f32x4 f0 = fzero4(), f1 = fzero4(), g0 = fzero4(), g1 = fzero4();
      #pragma unroll
      for (int ks = 0; ks < 8; ks += 2) {
        f0 = MFMA16x32(vaB[ks], vbf[ks], f0);
        g0 = MFMA16x32(vaB[ks], vba[ks], g0);
        f1 = MFMA16x32(vaB[ks + 1], vbf[ks + 1], f1);
        g1 = MFMA16x32(vaB[ks + 1], vba[ks + 1], g1);
      }
      const int rin = base + mo + 16 + kb * 4;
      #pragma unroll
      for (int r = 0; r < 4; ++r)
        if (rin + r < 5096)
          colsum += sigmoidf_(g0[r] + g1[r] + bav) * (f0[r] + f1[r] + bfv);
    }
  }
  colsum += __shfl_xor(colsum, 16);
  colsum += __shfl_xor(colsum, 32);
  if (l < 16) atomicAdd(&xf[(size_t)b * 512 + col], colsum);
}

// --------------------------------------------------------------------------
// Head: BN + dense(512->200) + softmax.
// --------------------------------------------------------------------------
__global__ __launch_bounds__(256) void head_k(const float* __restrict__ xf,
    const float* __restrict__ gamma, const float* __restrict__ beta,
    const float* __restrict__ mean, const float* __restrict__ var,
    const float* __restrict__ Wd, const float* __restrict__ bd,
    float* __restrict__ out) {
  const int b = blockIdx.x;
  const int tid = threadIdx.x;
  __shared__ float xn[512];
  __shared__ float red[256];
  for (int i = tid; i < 512; i += 256) {
    const float v = xf[(size_t)b * 512 + i];
    xn[i] = (v - mean[i]) / sqrtf(var[i] + 1e-3f) * gamma[i] + beta[i];
  }
  __syncthreads();
  float logit = -1e30f;
  if (tid < 200) {
    float acc = bd[tid];
    for (int i = 0; i < 512; ++i) acc = fmaf(xn[i], Wd[(size_t)i * 200 + tid], acc);
    logit = acc;
  }
  red[tid] = logit;
  __syncthreads();
  for (int off = 128; off; off >>= 1) {
    if (tid < off) red[tid] = fmaxf(red[tid], red[tid + off]);
    __syncthreads();
  }
  const float mx = red[0];
  __syncthreads();
  const float e = (tid < 200) ? expf(logit - mx) : 0.0f;
  red[tid] = e;
  __syncthreads();
  for (int off = 128; off; off >>= 1) {
    if (tid < off) red[tid] += red[tid + off];
    __syncthreads();
  }
  const float inv = 1.0f / red[0];
  if (tid < 200) out[(size_t)b * 200 + tid] = e * inv;
}

// ---------------------------------------------------------------------------
extern "C" void kernel_launch(void* const* d_in, const int* in_sizes, int n_in,
                              void* d_out, int out_size, void* d_ws, size_t ws_size,
                              hipStream_t stream) {
  (void)n_in; (void)out_size; (void)ws_size;
  const float* base    = (const float*)d_in[0];
  const float* appnp_w = (const float*)d_in[1];
  const float* appnp_b = (const float*)d_in[2];
  const float* gat_k   = (const float*)d_in[3];
  const float* gat_as  = (const float*)d_in[4];
  const float* gat_an  = (const float*)d_in[5];
  const float* gat_b   = (const float*)d_in[6];
  const float* pf_w    = (const float*)d_in[7];
  const float* pf_b    = (const float*)d_in[8];
  const float* pa_w    = (const float*)d_in[9];
  const float* pa_b    = (const float*)d_in[10];
  const float* bn_g    = (const float*)d_in[11];
  const float* bn_be   = (const float*)d_in[12];
  const float* bn_mu   = (const float*)d_in[13];
  const float* bn_va   = (const float*)d_in[14];
  const float* dw      = (const float*)d_in[15];
  const float* db      = (const float*)d_in[16];
  float* out = (float*)d_out;

  const int B = in_sizes[0] / (49 * 2048);   // 8
  const int G = B * 13;                      // 104 intra graphs
  const int R = G * 392;                     // 40768 node rows per branch
  const int MP = 2 * B * 5120;               // padded pool rows (81920)

  char* ws = (char*)d_ws;
  size_t off = 0;
  auto alloc = [&](size_t bytes) -> void* {
    void* p = (void*)(ws + off);
    off += (bytes + 255) & ~(size_t)255;
    return p;
  };
  float* wtab   = (float*)alloc((size_t)13 * 2 * 49 * 4);
  short* aWhi   = (short*)alloc((size_t)256 * 256 * 2);
  short* gkhi   = (short*)alloc((size_t)256 * 256 * 2);
  short* pfhi   = (short*)alloc((size_t)512 * 256 * 2);
  short* pahi   = (short*)alloc((size_t)512 * 256 * 2);
  float* was    = (float*)alloc((size_t)256 * 4);
  float* wan    = (float*)alloc((size_t)256 * 4);
  short* nodes  = (short*)alloc((size_t)R * 256 * 2);
  short* mbuf   = (short*)alloc((size_t)R * 256 * 2);
  short* hbuf   = (short*)alloc((size_t)R * 256 * 2);
  short* xpbuf  = (short*)alloc((size_t)R * 256 * 2);            // xp row-major
  short* xpT    = (short*)alloc((size_t)G * 256 * 416 * 2);      // intra xp^T
  short* Ebuf   = (short*)alloc((size_t)G * 512 * 416 * 2);
  short* x2buf  = (short*)alloc((size_t)MP * 256 * 2);           // padded segs
  float* Sintra = (float*)alloc((size_t)G * 256 * 4);
  float* Sinter = (float*)alloc((size_t)B * 392 * 256 * 4);
  float* sbuf   = (float*)alloc((size_t)R * 4);
  float* tbuf   = (float*)alloc((size_t)R * 4);
  float* dinv   = (float*)alloc((size_t)R * 4);
  float* xf     = (float*)alloc((size_t)B * 512 * 4);

  hipMemsetAsync(xf, 0, (size_t)B * 512 * 4, stream);
  wtab_k<<<1, 256, 0, stream>>>(wtab);
  wcvt_k<<<(256 * 256 + 255) / 256, 256, 0, stream>>>(appnp_w, aWhi, 256, 256);
  wcvt_k<<<(256 * 256 + 255) / 256, 256, 0, stream>>>(gat_k, gkhi, 256, 256);
  wcvt_k<<<(256 * 512 + 255) / 256, 256, 0, stream>>>(pf_w, pfhi, 256, 512);
  wcvt_k<<<(256 * 512 + 255) / 256, 256, 0, stream>>>(pa_w, pahi, 256, 512);
  wvec_k<<<64, 256, 0, stream>>>(gat_k, gat_as, gat_an, was, wan);
  nodes_k<<<B * 13 * 8, 256, 0, stream>>>(base, wtab, nodes);

  // m = sigmoid(nodes @ appnp_w + b)  (shared by both branches)
  gemm_rb_k<1><<<dim3((R + 127) / 128, 4), 256, 0, stream>>>(nodes, aWhi, appnp_b, mbuf, R);
  sums_intra_k<<<G, 256, 0, stream>>>(mbuf, Sintra);
  sums_inter_k<<<B * 392, 256, 0, stream>>>(mbuf, Sinter);

  // ---- intra branch ----
  h_intra_v<<<R / 8, 256, 0, stream>>>(nodes, mbuf, Sintra, hbuf);
  gemm_rb_k<0><<<dim3((R + 127) / 128, 4), 256, 0, stream>>>(hbuf, gkhi, nullptr, xpbuf, R);
  st_h_k<<<R / 4, 256, 0, stream>>>(hbuf, was, wan, sbuf, tbuf, R);
  transpose_k<<<dim3(7, 4, G), 256, 0, stream>>>(xpbuf, xpT);
  attn_e_k<<<dim3(14, G), 256, 0, stream>>>(sbuf, tbuf, Ebuf, dinv);
  pv_rb_k<<<dim3(4, 2, G), 256, 0, stream>>>(Ebuf, xpT, dinv, gat_b, hbuf, x2buf);

  // ---- inter branch ----
  h_inter_v<<<R / 8, 256, 0, stream>>>(nodes, mbuf, Sinter, hbuf);
  gemm_rb_k<0><<<dim3((R + 127) / 128, 4), 256, 0, stream>>>(hbuf, gkhi, nullptr, xpbuf, R);
  st_h_k<<<R / 4, 256, 0, stream>>>(hbuf, was, wan, sbuf, tbuf, R);
  attn_inter_k<<<B * 392, 256, 0, stream>>>(xpbuf, sbuf, tbuf, hbuf, gat_b, x2buf, B);

  // ---- pool + head ----
  pool_rb_k<<<dim3(MP / 512, 8), 256, 0, stream>>>(x2buf, pfhi, pf_b, pahi, pa_b, xf, B);
  head_k<<<B, 256, 0, stream>>>(xf, bn_g, bn_be, bn_mu, bn_va, dw, db, out);
}

// Round 6
// 432.046 us; speedup vs baseline: 1.3642x; 1.3642x over previous
//
#include <hip/hip_runtime.h>
#include <math.h>

// ---------------------------------------------------------------------------
// I2HOFI forward. B=8, 13 ROI graphs x 392 nodes (intra) / 392 x 13 (inter),
// feature 256. All big GEMMs: m97-style 128x128 LDS-tiled bf16 MFMA (BK=32,
// reg-prefetch staging, 4 waves x 64x64 quadrant, 4x4 f32x4 acc).
// Node row layout: row = (b*13 + r)*392 + c.
// x2 rows padded per (branch,b) segment: seg*5120 + within (within < 5096).
// ---------------------------------------------------------------------------

typedef __attribute__((ext_vector_type(8))) short bf16x8;
typedef __attribute__((ext_vector_type(4))) float f32x4;
typedef __attribute__((ext_vector_type(4))) short short4v;

#define MFMA16x32(a, b, c) __builtin_amdgcn_mfma_f32_16x16x32_bf16((a), (b), (c), 0, 0, 0)

__device__ __forceinline__ float sigmoidf_(float x) { return 1.0f / (1.0f + expf(-x)); }
__device__ __forceinline__ float leakyf_(float x) { return x >= 0.0f ? x : 0.2f * x; }
__device__ __forceinline__ float eluf_(float x) { return x > 0.0f ? x : expm1f(x); }
__device__ __forceinline__ short f2bf(float f) {
  unsigned u = __builtin_bit_cast(unsigned, f);
  unsigned r = u + 0x7fffu + ((u >> 16) & 1u);
  return (short)(r >> 16);
}
__device__ __forceinline__ float bf2f(short s) {
  unsigned u = ((unsigned)(unsigned short)s) << 16;
  return __builtin_bit_cast(float, u);
}
__device__ __forceinline__ f32x4 fzero4() {
  f32x4 z;
  #pragma unroll
  for (int i = 0; i < 4; ++i) z[i] = 0.0f;
  return z;
}

// --------------------------------------------------------------------------
// K0: composed resize weight tables. wtab[roi][axis][o][ib], 13*2*7*7.
// --------------------------------------------------------------------------
__global__ void wtab_k(float* __restrict__ wtab) {
  const int RX[12] = {0,14,28, 0,14,28, 0,14,28, 0, 0, 0};
  const int RY[12] = {0, 0, 0,14,14,14,28,28,28, 0,21, 0};
  const int RW[12] = {14,14,14,14,14,14,14,14,14,42,42,42};
  const int RH[12] = {14,14,14,14,14,14,14,14,14,21,21,42};
  for (int e = threadIdx.x; e < 13 * 2 * 49; e += blockDim.x) {
    const int roi = e / 98;
    const int rest = e % 98;
    const int axis = rest / 49;
    const int o = (rest % 49) / 7;
    const int ib = rest % 7;
    float wout;
    if (roi == 12) {
      wout = (o == ib) ? 1.0f : 0.0f;
    } else {
      const int start = axis ? RX[roi] : RY[roi];
      const int len = axis ? RW[roi] : RH[roi];
      const float s = (float)len / 7.0f;
      const float oc = (o + 0.5f) * s - 0.5f;
      float wsum = 0.0f, dot = 0.0f;
      for (int j = 0; j < len; ++j) {
        float w = 1.0f - fabsf((float)j - oc) / s;
        if (w <= 0.0f) continue;
        wsum += w;
        const float ic = ((float)(start + j) + 0.5f) / 6.0f - 0.5f;
        const float fl = floorf(ic);
        const int ia = (int)fl;
        const float fr = ic - fl;
        int c0 = ia;     if (c0 < 0) c0 = 0; if (c0 > 6) c0 = 6;
        int c1 = ia + 1; if (c1 < 0) c1 = 0; if (c1 > 6) c1 = 6;
        float u = 0.0f;
        if (c0 == ib) u += 1.0f - fr;
        if (c1 == ib) u += fr;
        dot += w * u;
      }
      wout = dot / wsum;
    }
    wtab[e] = wout;
  }
}

// --------------------------------------------------------------------------
// Weight transpose + bf16 convert: dst[n][k] from src[k][n] fp32.
// --------------------------------------------------------------------------
__global__ void wcvt_k(const float* __restrict__ src, short* __restrict__ hi,
                       int K, int N) {
  const int idx = blockIdx.x * 256 + threadIdx.x;
  if (idx >= K * N) return;
  const int k = idx / N, n = idx % N;
  hi[(size_t)n * K + k] = f2bf(src[idx]);
}

// --------------------------------------------------------------------------
// Pool combined weights, feat/gate 16-col groups interleaved:
// BT[n][k]: p=n>>4, i=n&15; p even -> Wf col ((p>>1)*16+i), p odd -> Wa.
// --------------------------------------------------------------------------
__global__ void wcvt_pool_k(const float* __restrict__ Wf, const float* __restrict__ Wa,
                            short* __restrict__ BT) {
  const int idx = blockIdx.x * 256 + threadIdx.x;
  if (idx >= 1024 * 256) return;
  const int n = idx >> 8, k = idx & 255;
  const int p = n >> 4, i = n & 15;
  const int sc = ((p >> 1) << 4) + i;
  const float v = (p & 1) ? Wa[(size_t)k * 512 + sc] : Wf[(size_t)k * 512 + sc];
  BT[(size_t)n * 256 + k] = f2bf(v);
}

// --------------------------------------------------------------------------
// was = gat_k @ a_self, wan = gat_k @ a_neigh (fp32). Wave per row.
// --------------------------------------------------------------------------
__global__ void wvec_k(const float* __restrict__ Wk, const float* __restrict__ as,
                       const float* __restrict__ an, float* __restrict__ was,
                       float* __restrict__ wan) {
  const int w = threadIdx.x >> 6, l = threadIdx.x & 63;
  const int row = blockIdx.x * 4 + w;
  const float* p = Wk + (size_t)row * 256;
  float s = 0.0f, t = 0.0f;
  #pragma unroll
  for (int j = 0; j < 4; ++j) {
    const int o = l + j * 64;
    const float v = p[o];
    s = fmaf(v, as[o], s);
    t = fmaf(v, an[o], t);
  }
  #pragma unroll
  for (int off = 32; off; off >>= 1) { s += __shfl_down(s, off); t += __shfl_down(t, off); }
  if (l == 0) { was[row] = s; wan[row] = t; }
}

// --------------------------------------------------------------------------
// K1: nodes (bf16) via separable 49x49 resize contraction.
// --------------------------------------------------------------------------
__global__ __launch_bounds__(256) void nodes_k(const float* __restrict__ base,
                                               const float* __restrict__ wtab,
                                               short* __restrict__ nodes) {
  const int blk = blockIdx.x;
  const int chunk = blk & 7;
  const int br = blk >> 3;
  const int r = br % 13;
  const int b = br / 13;
  const int f = threadIdx.x;
  __shared__ float W49[49][50];
  const float* wv = wtab + (r * 2 + 0) * 49;
  const float* wh = wtab + (r * 2 + 1) * 49;
  for (int e = f; e < 2401; e += 256) {
    const int o = e / 49, in = e % 49;
    W49[o][in] = wv[(o / 7) * 7 + in / 7] * wh[(o % 7) * 7 + in % 7];
  }
  __syncthreads();
  float bv[49];
  const float* bp = base + (size_t)b * 49 * 2048 + chunk * 256 + f;
  #pragma unroll
  for (int in = 0; in < 49; ++in) bv[in] = bp[(size_t)in * 2048];
  const size_t obase = ((size_t)(b * 13 + r) * 392 + chunk * 49) * 256 + f;
  for (int o = 0; o < 49; ++o) {
    float acc = 0.0f;
    #pragma unroll
    for (int in = 0; in < 49; ++in) acc = fmaf(W49[o][in], bv[in], acc);
    nodes[obase + (size_t)o * 256] = f2bf(acc);
  }
}

// --------------------------------------------------------------------------
// Tiled MFMA GEMM, m97 structure: 128x128 tile, BK=32, 4 waves (2x2 quads),
// global->reg->LDS staging (reg prefetch of next K-tile overlaps compute).
// A [*][Kpad] K-contig, BT [N][Kpad] K-contig. N: 256 (PLAIN/SIG/PV), 1024
// (POOL). Epilogues:
//  EP_PLAIN: bf16 store C[row][col], row < Mvalid
//  EP_SIG:   sigmoid(acc + e0[col])
//  EP_PV:    per-graph (grid.z): o=acc*dinv; elu(o+bias)+h residual -> x2
//  EP_POOL:  paired feat/gate cols -> sigmoid(gate)*feat, row-reduce,
//            atomicAdd into xf[seg%8][col]; XCD-chunked block swizzle.
// --------------------------------------------------------------------------
enum { EP_PLAIN = 0, EP_SIG = 1, EP_PV = 2, EP_POOL = 3 };

template <int EPI>
__global__ __launch_bounds__(256) void gemm_t(
    const short* __restrict__ A, const short* __restrict__ BT,
    const int Kpad, const int nkt, const int Mvalid,
    const float* __restrict__ e0, const float* __restrict__ e1,
    const short* __restrict__ e2, short* __restrict__ Cs,
    float* __restrict__ xf) {
  const int tid = threadIdx.x;
  const int w = tid >> 6, l = tid & 63;
  const int lr = l & 15, kb = l >> 4;
  const int wr = w >> 1, wc = w & 1;

  int row0, col0, g = 0, rbase = 0, bseg = 0;
  const short* Ap;
  const short* Bp;
  if constexpr (EPI == EP_POOL) {
    const int bid = blockIdx.x;
    const int eff = (bid & 7) * 640 + (bid >> 3);   // XCD-chunked swizzle
    const int mt = eff >> 3, ct = eff & 7;
    row0 = mt * 128; col0 = ct * 128;
    rbase = (mt % 40) * 128;
    bseg = (mt / 40) & 7;
    Ap = A; Bp = BT;
  } else if constexpr (EPI == EP_PV) {
    g = blockIdx.z;
    row0 = blockIdx.x * 128; col0 = blockIdx.y * 128;
    Ap = A + (size_t)g * 512 * 448;
    Bp = BT + (size_t)g * 256 * 448;
  } else {
    row0 = blockIdx.x * 128; col0 = blockIdx.y * 128;
    Ap = A; Bp = BT;
  }

  __shared__ short As[128][32];
  __shared__ short Bs[128][32];

  const int srow = w * 32 + (l >> 2);
  const int sso = (l & 3) * 8;
  const short* ag0 = Ap + (size_t)(row0 + srow) * Kpad + sso;
  const short* ag1 = ag0 + (size_t)16 * Kpad;
  const short* bg0 = Bp + (size_t)(col0 + srow) * Kpad + sso;
  const short* bg1 = bg0 + (size_t)16 * Kpad;

  f32x4 acc[4][4];
  #pragma unroll
  for (int i = 0; i < 4; ++i)
    #pragma unroll
    for (int j = 0; j < 4; ++j) acc[i][j] = fzero4();

  bf16x8 ra0 = *(const bf16x8*)ag0;
  bf16x8 ra1 = *(const bf16x8*)ag1;
  bf16x8 rb0 = *(const bf16x8*)bg0;
  bf16x8 rb1 = *(const bf16x8*)bg1;

  for (int kt = 0; kt < nkt; ++kt) {
    __syncthreads();
    *(bf16x8*)&As[srow][sso] = ra0;
    *(bf16x8*)&As[srow + 16][sso] = ra1;
    *(bf16x8*)&Bs[srow][sso] = rb0;
    *(bf16x8*)&Bs[srow + 16][sso] = rb1;
    if (kt + 1 < nkt) {
      const int ko = (kt + 1) * 32;
      ra0 = *(const bf16x8*)(ag0 + ko);
      ra1 = *(const bf16x8*)(ag1 + ko);
      rb0 = *(const bf16x8*)(bg0 + ko);
      rb1 = *(const bf16x8*)(bg1 + ko);
    }
    __syncthreads();
    bf16x8 va[4], vb[4];
    #pragma unroll
    for (int i = 0; i < 4; ++i) va[i] = *(const bf16x8*)&As[wr * 64 + i * 16 + lr][kb * 8];
    #pragma unroll
    for (int j = 0; j < 4; ++j) vb[j] = *(const bf16x8*)&Bs[wc * 64 + j * 16 + lr][kb * 8];
    #pragma unroll
    for (int i = 0; i < 4; ++i)
      #pragma unroll
      for (int j = 0; j < 4; ++j) acc[i][j] = MFMA16x32(va[i], vb[j], acc[i][j]);
  }

  if constexpr (EPI == EP_PLAIN || EPI == EP_SIG) {
    #pragma unroll
    for (int j = 0; j < 4; ++j) {
      const int col = col0 + wc * 64 + j * 16 + lr;
      float bs = 0.0f;
      if constexpr (EPI == EP_SIG) bs = e0[col];
      #pragma unroll
      for (int i = 0; i < 4; ++i) {
        const int row = row0 + wr * 64 + i * 16 + kb * 4;
        #pragma unroll
        for (int r = 0; r < 4; ++r) {
          if (row + r < Mvalid) {
            float o = acc[i][j][r];
            if constexpr (EPI == EP_SIG) o = sigmoidf_(o + bs);
            Cs[(size_t)(row + r) * 256 + col] = f2bf(o);
          }
        }
      }
    }
  } else if constexpr (EPI == EP_PV) {
    const int bb = g / 13, rr = g % 13;
    #pragma unroll
    for (int j = 0; j < 4; ++j) {
      const int col = col0 + wc * 64 + j * 16 + lr;
      const float bv = e1[col];
      #pragma unroll
      for (int i = 0; i < 4; ++i) {
        const int rl = row0 + wr * 64 + i * 16 + kb * 4;
        #pragma unroll
        for (int r = 0; r < 4; ++r) {
          const int row = rl + r;
          if (row < 392) {
            const size_t grow = (size_t)g * 392 + row;
            const float o = acc[i][j][r] * e0[grow];
            const float val = eluf_(o + bv) + bf2f(e2[grow * 256 + col]);
            Cs[((size_t)bb * 5120 + rr * 392 + row) * 256 + col] = f2bf(val);
          }
        }
      }
    }
  } else {  // EP_POOL
    #pragma unroll
    for (int jp = 0; jp < 2; ++jp) {
      const int j = jp * 2;
      const int cg = col0 + wc * 64 + j * 16;        // feat group base
      const int realcol = ((cg >> 5) << 4) + lr;
      const float bfv = e0[realcol], bav = e1[realcol];
      float cs = 0.0f;
      #pragma unroll
      for (int i = 0; i < 4; ++i) {
        const int rl = rbase + wr * 64 + i * 16 + kb * 4;
        #pragma unroll
        for (int r = 0; r < 4; ++r) {
          if (rl + r < 5096) {
            const float fv = acc[i][j][r] + bfv;
            const float gv = acc[i][j + 1][r] + bav;
            cs += sigmoidf_(gv) * fv;
          }
        }
      }
      cs += __shfl_xor(cs, 16);
      cs += __shfl_xor(cs, 32);
      if (l < 16) atomicAdd(&xf[(size_t)bseg * 512 + realcol], cs);
    }
  }
}

// --------------------------------------------------------------------------
// Transpose xp[g][392][256] -> xpT[g][256][448] (cols 392..447 zero).
// --------------------------------------------------------------------------
__global__ __launch_bounds__(256) void transpose_k(const short* __restrict__ xp,
                                                   short* __restrict__ xpT) {
  const int m0 = blockIdx.x * 64;
  const int f0 = blockIdx.y * 64;
  const int g = blockIdx.z;
  const int tid = threadIdx.x;
  __shared__ short tile[64][66];
  const int c = tid & 63;
  const int r4 = tid >> 6;
  #pragma unroll
  for (int p = 0; p < 16; ++p) {
    const int row = p * 4 + r4;
    const int m = m0 + row;
    tile[row][c] = (m < 392) ? xp[((size_t)g * 392 + m) * 256 + f0 + c] : (short)0;
  }
  __syncthreads();
  #pragma unroll
  for (int p = 0; p < 16; ++p) {
    const int fr = p * 4 + r4;
    xpT[((size_t)g * 256 + f0 + fr) * 448 + m0 + c] = tile[c][fr];
  }
}

// --------------------------------------------------------------------------
// Graph feature sums of m (bf16 in, fp32 out).
// --------------------------------------------------------------------------
__global__ void sums_intra_k(const short* __restrict__ m, float* __restrict__ S) {
  const int g = blockIdx.x;
  const int f = threadIdx.x;
  const short* p = m + (size_t)g * 392 * 256 + f;
  float a0 = 0.0f, a1 = 0.0f, a2 = 0.0f, a3 = 0.0f;
  for (int c = 0; c < 392; c += 4) {
    a0 += bf2f(p[(size_t)(c + 0) * 256]);
    a1 += bf2f(p[(size_t)(c + 1) * 256]);
    a2 += bf2f(p[(size_t)(c + 2) * 256]);
    a3 += bf2f(p[(size_t)(c + 3) * 256]);
  }
  S[(size_t)g * 256 + f] = (a0 + a1) + (a2 + a3);
}

__global__ void sums_inter_k(const short* __restrict__ m, float* __restrict__ S) {
  const int g = blockIdx.x;
  const int b = g / 392, c = g % 392;
  const int f = threadIdx.x;
  const short* p = m + ((size_t)(b * 13) * 392 + c) * 256 + f;
  float acc = 0.0f;
  #pragma unroll
  for (int r = 0; r < 13; ++r) acc += bf2f(p[(size_t)r * 392 * 256]);
  S[(size_t)g * 256 + f] = acc;
}

// --------------------------------------------------------------------------
// h = 0.9*(S_g + m)/(n+1) + 0.1*m + x  (APPNP + residual), bf16x8 vectorized.
// --------------------------------------------------------------------------
__global__ void h_intra_v(const short* __restrict__ nodes, const short* __restrict__ m,
                          const float* __restrict__ S, short* __restrict__ h) {
  const size_t e0 = ((size_t)blockIdx.x * 256 + threadIdx.x) * 8;
  const int row = (int)(e0 >> 8);
  const int f0 = (int)(e0 & 255);
  const int g = row / 392;
  const bf16x8 mv8 = *(const bf16x8*)(m + e0);
  const bf16x8 nv8 = *(const bf16x8*)(nodes + e0);
  const float* Sp = S + (size_t)g * 256 + f0;
  bf16x8 o;
  #pragma unroll
  for (int i = 0; i < 8; ++i) {
    const float mv = bf2f(mv8[i]);
    o[i] = f2bf(0.9f * (Sp[i] + mv) * (1.0f / 393.0f) + 0.1f * mv + bf2f(nv8[i]));
  }
  *(bf16x8*)(h + e0) = o;
}

__global__ void h_inter_v(const short* __restrict__ nodes, const short* __restrict__ m,
                          const float* __restrict__ S, short* __restrict__ h) {
  const size_t e0 = ((size_t)blockIdx.x * 256 + threadIdx.x) * 8;
  const int row = (int)(e0 >> 8);
  const int f0 = (int)(e0 & 255);
  const int b = row / 5096;
  const int c = row % 392;
  const int g = b * 392 + c;
  const bf16x8 mv8 = *(const bf16x8*)(m + e0);
  const bf16x8 nv8 = *(const bf16x8*)(nodes + e0);
  const float* Sp = S + (size_t)g * 256 + f0;
  bf16x8 o;
  #pragma unroll
  for (int i = 0; i < 8; ++i) {
    const float mv = bf2f(mv8[i]);
    o[i] = f2bf(0.9f * (Sp[i] + mv) * (1.0f / 14.0f) + 0.1f * mv + bf2f(nv8[i]));
  }
  *(bf16x8*)(h + e0) = o;
}

// --------------------------------------------------------------------------
// Attention scalars from h: s = h . was, t = h . wan.
// --------------------------------------------------------------------------
__global__ void st_h_k(const short* __restrict__ h, const float* __restrict__ was,
                       const float* __restrict__ wan, float* __restrict__ sb,
                       float* __restrict__ tb, int M) {
  const int row = (int)(((size_t)blockIdx.x * blockDim.x + threadIdx.x) >> 6);
  const int lane = threadIdx.x & 63;
  if (row >= M) return;
  const short4v v = *(const short4v*)(h + (size_t)row * 256 + lane * 4);
  float s = 0.0f, t = 0.0f;
  #pragma unroll
  for (int j = 0; j < 4; ++j) {
    const float x = bf2f(v[j]);
    s = fmaf(x, was[lane * 4 + j], s);
    t = fmaf(x, wan[lane * 4 + j], t);
  }
  #pragma unroll
  for (int off = 32; off; off >>= 1) { s += __shfl_down(s, off); t += __shfl_down(t, off); }
  if (lane == 0) { sb[row] = s; tb[row] = t; }
}

// --------------------------------------------------------------------------
// Intra E (bf16, [g][512 rows][448 K]; rows<448 written, cols>=392 zero) +
// 1/denom. Vectorized bf16x8 row writes.
// --------------------------------------------------------------------------
__global__ __launch_bounds__(256) void attn_e_k(const float* __restrict__ sb,
    const float* __restrict__ tb, short* __restrict__ E, float* __restrict__ dinv) {
  const int g = blockIdx.y;
  const int n0 = blockIdx.x * 32;
  const int tid = threadIdx.x;
  __shared__ float t_s[392];
  __shared__ float red[256];
  for (int i = tid; i < 392; i += 256) t_s[i] = tb[(size_t)g * 392 + i];
  __syncthreads();
  float lm = -1e30f;
  for (int i = tid; i < 392; i += 256) lm = fmaxf(lm, t_s[i]);
  red[tid] = lm;
  __syncthreads();
  for (int off = 128; off; off >>= 1) {
    if (tid < off) red[tid] = fmaxf(red[tid], red[tid + off]);
    __syncthreads();
  }
  const float tmax = red[0];
  const int n = n0 + (tid >> 3);
  const int ml = tid & 7;
  const bool nv = (n < 392);
  const float sv = nv ? sb[(size_t)g * 392 + n] : 0.0f;
  const float lt = leakyf_(sv + tmax);
  float d = 0.0f;
  short* erow = E + ((size_t)g * 512 + n) * 448;
  for (int c = 0; c < 7; ++c) {
    const int mb = c * 64 + ml * 8;
    bf16x8 ev;
    #pragma unroll
    for (int i = 0; i < 8; ++i) {
      const int m = mb + i;
      float e = 0.0f;
      if (nv && m < 392) { e = expf(leakyf_(sv + t_s[m]) - lt); d += e; }
      ev[i] = f2bf(e);
    }
    *(bf16x8*)(erow + mb) = ev;
  }
  d += __shfl_xor(d, 1); d += __shfl_xor(d, 2); d += __shfl_xor(d, 4);
  if (nv && ml == 0) dinv[(size_t)g * 392 + n] = 1.0f / d;
}

// --------------------------------------------------------------------------
// Inter attention: 13-node graphs, one block per (b,c).
// --------------------------------------------------------------------------
__global__ __launch_bounds__(256) void attn_inter_k(const short* __restrict__ xp,
    const float* __restrict__ sb, const float* __restrict__ tb,
    const short* __restrict__ h, const float* __restrict__ bias,
    short* __restrict__ x2, int B) {
  const int g = blockIdx.x;
  const int b = g / 392, c = g % 392;
  const int tid = threadIdx.x;
  __shared__ float xps[13][256];
  __shared__ float e_s[13][14];
  __shared__ float sv[13], tv[13], denom[13];
  __shared__ float tmax_s;
  for (int lin = tid; lin < 13 * 256; lin += 256) {
    const int r = lin >> 8, f = lin & 255;
    xps[r][f] = bf2f(xp[((size_t)(b * 13 + r) * 392 + c) * 256 + f]);
  }
  if (tid < 13) {
    const size_t row = (size_t)(b * 13 + tid) * 392 + c;
    sv[tid] = sb[row];
    tv[tid] = tb[row];
  }
  __syncthreads();
  if (tid == 0) {
    float mx = tv[0];
    for (int r = 1; r < 13; ++r) mx = fmaxf(mx, tv[r]);
    tmax_s = mx;
  }
  __syncthreads();
  if (tid < 169) {
    const int n = tid / 13, mm = tid % 13;
    e_s[n][mm] = expf(leakyf_(sv[n] + tv[mm]) - leakyf_(sv[n] + tmax_s));
  }
  __syncthreads();
  if (tid < 13) {
    float d = 0.0f;
    for (int mm = 0; mm < 13; ++mm) d += e_s[tid][mm];
    denom[tid] = d;
  }
  __syncthreads();
  const int f = tid;
  for (int n = 0; n < 13; ++n) {
    float acc = 0.0f;
    #pragma unroll
    for (int mm = 0; mm < 13; ++mm) acc = fmaf(e_s[n][mm], xps[mm][f], acc);
    const float o = acc / denom[n];
    const size_t hbase = ((size_t)(b * 13 + n) * 392 + c) * 256 + f;
    x2[(((size_t)(B + b)) * 5120 + (size_t)n * 392 + c) * 256 + f] =
        f2bf(eluf_(o + bias[f]) + bf2f(h[hbase]));
  }
}

// --------------------------------------------------------------------------
// Head: BN + dense(512->200) + softmax.
// --------------------------------------------------------------------------
__global__ __launch_bounds__(256) void head_k(const float* __restrict__ xf,
    const float* __restrict__ gamma, const float* __restrict__ beta,
    const float* __restrict__ mean, const float* __restrict__ var,
    const float* __restrict__ Wd, const float* __restrict__ bd,
    float* __restrict__ out) {
  const int b = blockIdx.x;
  const int tid = threadIdx.x;
  __shared__ float xn[512];
  __shared__ float red[256];
  for (int i = tid; i < 512; i += 256) {
    const float v = xf[(size_t)b * 512 + i];
    xn[i] = (v - mean[i]) / sqrtf(var[i] + 1e-3f) * gamma[i] + beta[i];
  }
  __syncthreads();
  float logit = -1e30f;
  if (tid < 200) {
    float acc = bd[tid];
    for (int i = 0; i < 512; ++i) acc = fmaf(xn[i], Wd[(size_t)i * 200 + tid], acc);
    logit = acc;
  }
  red[tid] = logit;
  __syncthreads();
  for (int off = 128; off; off >>= 1) {
    if (tid < off) red[tid] = fmaxf(red[tid], red[tid + off]);
    __syncthreads();
  }
  const float mx = red[0];
  __syncthreads();
  const float e = (tid < 200) ? expf(logit - mx) : 0.0f;
  red[tid] = e;
  __syncthreads();
  for (int off = 128; off; off >>= 1) {
    if (tid < off) red[tid] += red[tid + off];
    __syncthreads();
  }
  const float inv = 1.0f / red[0];
  if (tid < 200) out[(size_t)b * 200 + tid] = e * inv;
}

// ---------------------------------------------------------------------------
extern "C" void kernel_launch(void* const* d_in, const int* in_sizes, int n_in,
                              void* d_out, int out_size, void* d_ws, size_t ws_size,
                              hipStream_t stream) {
  (void)n_in; (void)out_size; (void)ws_size;
  const float* base    = (const float*)d_in[0];
  const float* appnp_w = (const float*)d_in[1];
  const float* appnp_b = (const float*)d_in[2];
  const float* gat_k   = (const float*)d_in[3];
  const float* gat_as  = (const float*)d_in[4];
  const float* gat_an  = (const float*)d_in[5];
  const float* gat_b   = (const float*)d_in[6];
  const float* pf_w    = (const float*)d_in[7];
  const float* pf_b    = (const float*)d_in[8];
  const float* pa_w    = (const float*)d_in[9];
  const float* pa_b    = (const float*)d_in[10];
  const float* bn_g    = (const float*)d_in[11];
  const float* bn_be   = (const float*)d_in[12];
  const float* bn_mu   = (const float*)d_in[13];
  const float* bn_va   = (const float*)d_in[14];
  const float* dw      = (const float*)d_in[15];
  const float* db      = (const float*)d_in[16];
  float* out = (float*)d_out;

  const int B = in_sizes[0] / (49 * 2048);   // 8
  const int G = B * 13;                      // 104 intra graphs
  const int R = G * 392;                     // 40768 node rows per branch
  const int Mt = (R + 127) / 128;            // 319 row tiles
  const int Rpad = Mt * 128;                 // 40832 (A-panel slack)
  const int MP = 2 * B * 5120;               // padded pool rows (81920)

  char* ws = (char*)d_ws;
  size_t off = 0;
  auto alloc = [&](size_t bytes) -> void* {
    void* p = (void*)(ws + off);
    off += (bytes + 255) & ~(size_t)255;
    return p;
  };
  float* wtab   = (float*)alloc((size_t)13 * 2 * 49 * 4);
  short* aWhi   = (short*)alloc((size_t)256 * 256 * 2);
  short* gkhi   = (short*)alloc((size_t)256 * 256 * 2);
  short* pwcomb = (short*)alloc((size_t)1024 * 256 * 2);
  float* was    = (float*)alloc((size_t)256 * 4);
  float* wan    = (float*)alloc((size_t)256 * 4);
  short* nodes  = (short*)alloc((size_t)Rpad * 256 * 2);
  short* mbuf   = (short*)alloc((size_t)R * 256 * 2);
  short* hbuf   = (short*)alloc((size_t)Rpad * 256 * 2);
  short* xpbuf  = (short*)alloc((size_t)R * 256 * 2);
  short* xpT    = (short*)alloc((size_t)G * 256 * 448 * 2);
  short* Ebuf   = (short*)alloc((size_t)G * 512 * 448 * 2);
  short* x2buf  = (short*)alloc((size_t)MP * 256 * 2);
  float* Sintra = (float*)alloc((size_t)G * 256 * 4);
  float* Sinter = (float*)alloc((size_t)B * 392 * 256 * 4);
  float* sbuf   = (float*)alloc((size_t)R * 4);
  float* tbuf   = (float*)alloc((size_t)R * 4);
  float* dinv   = (float*)alloc((size_t)R * 4);
  float* xf     = (float*)alloc((size_t)B * 512 * 4);

  hipMemsetAsync(xf, 0, (size_t)B * 512 * 4, stream);
  wtab_k<<<1, 256, 0, stream>>>(wtab);
  wcvt_k<<<(256 * 256 + 255) / 256, 256, 0, stream>>>(appnp_w, aWhi, 256, 256);
  wcvt_k<<<(256 * 256 + 255) / 256, 256, 0, stream>>>(gat_k, gkhi, 256, 256);
  wcvt_pool_k<<<1024, 256, 0, stream>>>(pf_w, pa_w, pwcomb);
  wvec_k<<<64, 256, 0, stream>>>(gat_k, gat_as, gat_an, was, wan);
  nodes_k<<<B * 13 * 8, 256, 0, stream>>>(base, wtab, nodes);

  // m = sigmoid(nodes @ appnp_w + b)  (shared by both branches)
  gemm_t<EP_SIG><<<dim3(Mt, 2), 256, 0, stream>>>(nodes, aWhi, 256, 8, R,
      appnp_b, nullptr, nullptr, mbuf, nullptr);
  sums_intra_k<<<G, 256, 0, stream>>>(mbuf, Sintra);
  sums_inter_k<<<B * 392, 256, 0, stream>>>(mbuf, Sinter);

  // ---- intra branch ----
  h_intra_v<<<R / 8, 256, 0, stream>>>(nodes, mbuf, Sintra, hbuf);
  gemm_t<EP_PLAIN><<<dim3(Mt, 2), 256, 0, stream>>>(hbuf, gkhi, 256, 8, R,
      nullptr, nullptr, nullptr, xpbuf, nullptr);
  st_h_k<<<R / 4, 256, 0, stream>>>(hbuf, was, wan, sbuf, tbuf, R);
  transpose_k<<<dim3(7, 4, G), 256, 0, stream>>>(xpbuf, xpT);
  attn_e_k<<<dim3(14, G), 256, 0, stream>>>(sbuf, tbuf, Ebuf, dinv);
  gemm_t<EP_PV><<<dim3(4, 2, G), 256, 0, stream>>>(Ebuf, xpT, 448, 14, 392,
      dinv, gat_b, hbuf, x2buf, nullptr);

  // ---- inter branch ----
  h_inter_v<<<R / 8, 256, 0, stream>>>(nodes, mbuf, Sinter, hbuf);
  gemm_t<EP_PLAIN><<<dim3(Mt, 2), 256, 0, stream>>>(hbuf, gkhi, 256, 8, R,
      nullptr, nullptr, nullptr, xpbuf, nullptr);
  st_h_k<<<R / 4, 256, 0, stream>>>(hbuf, was, wan, sbuf, tbuf, R);
  attn_inter_k<<<B * 392, 256, 0, stream>>>(xpbuf, sbuf, tbuf, hbuf, gat_b, x2buf, B);

  // ---- pool + head ----
  gemm_t<EP_POOL><<<5120, 256, 0, stream>>>(x2buf, pwcomb, 256, 8, 0,
      pf_b, pa_b, nullptr, nullptr, xf);
  head_k<<<B, 256, 0, stream>>>(xf, bn_g, bn_be, bn_mu, bn_va, dw, db, out);
}

// Round 7
// 418.330 us; speedup vs baseline: 1.4089x; 1.0328x over previous
//
#include <hip/hip_runtime.h>
#include <math.h>

// ---------------------------------------------------------------------------
// I2HOFI forward. B=8, 13 ROI graphs x 392 nodes (intra) / 392 x 13 (inter),
// feature 256. Weight GEMMs + pool: m97-style 128x128 LDS-tiled bf16 MFMA.
// Intra GAT PV: flash-fused (E built on the fly in LDS from s,t scalars).
// Node row layout: row = (b*13 + r)*392 + c.
// x2 rows padded per (branch,b) segment: seg*5120 + within (within < 5096).
// ---------------------------------------------------------------------------

typedef __attribute__((ext_vector_type(8))) short bf16x8;
typedef __attribute__((ext_vector_type(4))) float f32x4;

#define MFMA16x32(a, b, c) __builtin_amdgcn_mfma_f32_16x16x32_bf16((a), (b), (c), 0, 0, 0)

__device__ __forceinline__ float sigmoidf_(float x) { return 1.0f / (1.0f + expf(-x)); }
__device__ __forceinline__ float leakyf_(float x) { return x >= 0.0f ? x : 0.2f * x; }
__device__ __forceinline__ float eluf_(float x) { return x > 0.0f ? x : expm1f(x); }
__device__ __forceinline__ short f2bf(float f) {
  unsigned u = __builtin_bit_cast(unsigned, f);
  unsigned r = u + 0x7fffu + ((u >> 16) & 1u);
  return (short)(r >> 16);
}
__device__ __forceinline__ float bf2f(short s) {
  unsigned u = ((unsigned)(unsigned short)s) << 16;
  return __builtin_bit_cast(float, u);
}
__device__ __forceinline__ f32x4 fzero4() {
  f32x4 z;
  #pragma unroll
  for (int i = 0; i < 4; ++i) z[i] = 0.0f;
  return z;
}

// --------------------------------------------------------------------------
// K0: composed resize weight tables. wtab[roi][axis][o][ib], 13*2*7*7.
// --------------------------------------------------------------------------
__global__ void wtab_k(float* __restrict__ wtab) {
  const int RX[12] = {0,14,28, 0,14,28, 0,14,28, 0, 0, 0};
  const int RY[12] = {0, 0, 0,14,14,14,28,28,28, 0,21, 0};
  const int RW[12] = {14,14,14,14,14,14,14,14,14,42,42,42};
  const int RH[12] = {14,14,14,14,14,14,14,14,14,21,21,42};
  for (int e = threadIdx.x; e < 13 * 2 * 49; e += blockDim.x) {
    const int roi = e / 98;
    const int rest = e % 98;
    const int axis = rest / 49;
    const int o = (rest % 49) / 7;
    const int ib = rest % 7;
    float wout;
    if (roi == 12) {
      wout = (o == ib) ? 1.0f : 0.0f;
    } else {
      const int start = axis ? RX[roi] : RY[roi];
      const int len = axis ? RW[roi] : RH[roi];
      const float s = (float)len / 7.0f;
      const float oc = (o + 0.5f) * s - 0.5f;
      float wsum = 0.0f, dot = 0.0f;
      for (int j = 0; j < len; ++j) {
        float w = 1.0f - fabsf((float)j - oc) / s;
        if (w <= 0.0f) continue;
        wsum += w;
        const float ic = ((float)(start + j) + 0.5f) / 6.0f - 0.5f;
        const float fl = floorf(ic);
        const int ia = (int)fl;
        const float fr = ic - fl;
        int c0 = ia;     if (c0 < 0) c0 = 0; if (c0 > 6) c0 = 6;
        int c1 = ia + 1; if (c1 < 0) c1 = 0; if (c1 > 6) c1 = 6;
        float u = 0.0f;
        if (c0 == ib) u += 1.0f - fr;
        if (c1 == ib) u += fr;
        dot += w * u;
      }
      wout = dot / wsum;
    }
    wtab[e] = wout;
  }
}

// --------------------------------------------------------------------------
// Weight transpose + bf16 convert: dst[n][k] from src[k][n] fp32.
// --------------------------------------------------------------------------
__global__ void wcvt_k(const float* __restrict__ src, short* __restrict__ hi,
                       int K, int N) {
  const int idx = blockIdx.x * 256 + threadIdx.x;
  if (idx >= K * N) return;
  const int k = idx / N, n = idx % N;
  hi[(size_t)n * K + k] = f2bf(src[idx]);
}

// --------------------------------------------------------------------------
// Pool combined weights, feat/gate 16-col groups interleaved:
// BT[n][k]: p=n>>4, i=n&15; p even -> Wf col ((p>>1)*16+i), p odd -> Wa.
// --------------------------------------------------------------------------
__global__ void wcvt_pool_k(const float* __restrict__ Wf, const float* __restrict__ Wa,
                            short* __restrict__ BT) {
  const int idx = blockIdx.x * 256 + threadIdx.x;
  if (idx >= 1024 * 256) return;
  const int n = idx >> 8, k = idx & 255;
  const int p = n >> 4, i = n & 15;
  const int sc = ((p >> 1) << 4) + i;
  const float v = (p & 1) ? Wa[(size_t)k * 512 + sc] : Wf[(size_t)k * 512 + sc];
  BT[(size_t)n * 256 + k] = f2bf(v);
}

// --------------------------------------------------------------------------
// was = gat_k @ a_self, wan = gat_k @ a_neigh (fp32). Wave per row.
// --------------------------------------------------------------------------
__global__ void wvec_k(const float* __restrict__ Wk, const float* __restrict__ as,
                       const float* __restrict__ an, float* __restrict__ was,
                       float* __restrict__ wan) {
  const int w = threadIdx.x >> 6, l = threadIdx.x & 63;
  const int row = blockIdx.x * 4 + w;
  const float* p = Wk + (size_t)row * 256;
  float s = 0.0f, t = 0.0f;
  #pragma unroll
  for (int j = 0; j < 4; ++j) {
    const int o = l + j * 64;
    const float v = p[o];
    s = fmaf(v, as[o], s);
    t = fmaf(v, an[o], t);
  }
  #pragma unroll
  for (int off = 32; off; off >>= 1) { s += __shfl_down(s, off); t += __shfl_down(t, off); }
  if (l == 0) { was[row] = s; wan[row] = t; }
}

// --------------------------------------------------------------------------
// K1: nodes (bf16) via separable 49x49 resize contraction.
// --------------------------------------------------------------------------
__global__ __launch_bounds__(256) void nodes_k(const float* __restrict__ base,
                                               const float* __restrict__ wtab,
                                               short* __restrict__ nodes) {
  const int blk = blockIdx.x;
  const int chunk = blk & 7;
  const int br = blk >> 3;
  const int r = br % 13;
  const int b = br / 13;
  const int f = threadIdx.x;
  __shared__ float W49[49][50];
  const float* wv = wtab + (r * 2 + 0) * 49;
  const float* wh = wtab + (r * 2 + 1) * 49;
  for (int e = f; e < 2401; e += 256) {
    const int o = e / 49, in = e % 49;
    W49[o][in] = wv[(o / 7) * 7 + in / 7] * wh[(o % 7) * 7 + in % 7];
  }
  __syncthreads();
  float bv[49];
  const float* bp = base + (size_t)b * 49 * 2048 + chunk * 256 + f;
  #pragma unroll
  for (int in = 0; in < 49; ++in) bv[in] = bp[(size_t)in * 2048];
  const size_t obase = ((size_t)(b * 13 + r) * 392 + chunk * 49) * 256 + f;
  for (int o = 0; o < 49; ++o) {
    float acc = 0.0f;
    #pragma unroll
    for (int in = 0; in < 49; ++in) acc = fmaf(W49[o][in], bv[in], acc);
    nodes[obase + (size_t)o * 256] = f2bf(acc);
  }
}

// --------------------------------------------------------------------------
// Tiled MFMA GEMM, m97 structure: 128x128 tile, BK=32, 4 waves (2x2 quads),
// global->reg->LDS staging. Epilogues: PLAIN / SIG / POOL.
// --------------------------------------------------------------------------
enum { EP_PLAIN = 0, EP_SIG = 1, EP_POOL = 3 };

template <int EPI>
__global__ __launch_bounds__(256) void gemm_t(
    const short* __restrict__ A, const short* __restrict__ BT,
    const int Kpad, const int nkt, const int Mvalid,
    const float* __restrict__ e0, const float* __restrict__ e1,
    short* __restrict__ Cs, float* __restrict__ xf) {
  const int tid = threadIdx.x;
  const int w = tid >> 6, l = tid & 63;
  const int lr = l & 15, kb = l >> 4;
  const int wr = w >> 1, wc = w & 1;

  int row0, col0, rbase = 0, bseg = 0;
  if constexpr (EPI == EP_POOL) {
    const int bid = blockIdx.x;
    const int eff = (bid & 7) * 640 + (bid >> 3);   // XCD-chunked swizzle
    const int mt = eff >> 3, ct = eff & 7;
    row0 = mt * 128; col0 = ct * 128;
    rbase = (mt % 40) * 128;
    bseg = (mt / 40) & 7;
  } else {
    row0 = blockIdx.x * 128; col0 = blockIdx.y * 128;
  }

  __shared__ short As[128][32];
  __shared__ short Bs[128][32];

  const int srow = w * 32 + (l >> 2);
  const int sso = (l & 3) * 8;
  const short* ag0 = A + (size_t)(row0 + srow) * Kpad + sso;
  const short* ag1 = ag0 + (size_t)16 * Kpad;
  const short* bg0 = BT + (size_t)(col0 + srow) * Kpad + sso;
  const short* bg1 = bg0 + (size_t)16 * Kpad;

  f32x4 acc[4][4];
  #pragma unroll
  for (int i = 0; i < 4; ++i)
    #pragma unroll
    for (int j = 0; j < 4; ++j) acc[i][j] = fzero4();

  bf16x8 ra0 = *(const bf16x8*)ag0;
  bf16x8 ra1 = *(const bf16x8*)ag1;
  bf16x8 rb0 = *(const bf16x8*)bg0;
  bf16x8 rb1 = *(const bf16x8*)bg1;

  for (int kt = 0; kt < nkt; ++kt) {
    __syncthreads();
    *(bf16x8*)&As[srow][sso] = ra0;
    *(bf16x8*)&As[srow + 16][sso] = ra1;
    *(bf16x8*)&Bs[srow][sso] = rb0;
    *(bf16x8*)&Bs[srow + 16][sso] = rb1;
    if (kt + 1 < nkt) {
      const int ko = (kt + 1) * 32;
      ra0 = *(const bf16x8*)(ag0 + ko);
      ra1 = *(const bf16x8*)(ag1 + ko);
      rb0 = *(const bf16x8*)(bg0 + ko);
      rb1 = *(const bf16x8*)(bg1 + ko);
    }
    __syncthreads();
    bf16x8 va[4], vb[4];
    #pragma unroll
    for (int i = 0; i < 4; ++i) va[i] = *(const bf16x8*)&As[wr * 64 + i * 16 + lr][kb * 8];
    #pragma unroll
    for (int j = 0; j < 4; ++j) vb[j] = *(const bf16x8*)&Bs[wc * 64 + j * 16 + lr][kb * 8];
    #pragma unroll
    for (int i = 0; i < 4; ++i)
      #pragma unroll
      for (int j = 0; j < 4; ++j) acc[i][j] = MFMA16x32(va[i], vb[j], acc[i][j]);
  }

  if constexpr (EPI == EP_PLAIN || EPI == EP_SIG) {
    #pragma unroll
    for (int j = 0; j < 4; ++j) {
      const int col = col0 + wc * 64 + j * 16 + lr;
      float bs = 0.0f;
      if constexpr (EPI == EP_SIG) bs = e0[col];
      #pragma unroll
      for (int i = 0; i < 4; ++i) {
        const int row = row0 + wr * 64 + i * 16 + kb * 4;
        #pragma unroll
        for (int r = 0; r < 4; ++r) {
          if (row + r < Mvalid) {
            float o = acc[i][j][r];
            if constexpr (EPI == EP_SIG) o = sigmoidf_(o + bs);
            Cs[(size_t)(row + r) * 256 + col] = f2bf(o);
          }
        }
      }
    }
  } else {  // EP_POOL
    #pragma unroll
    for (int jp = 0; jp < 2; ++jp) {
      const int j = jp * 2;
      const int cg = col0 + wc * 64 + j * 16;        // feat group base
      const int realcol = ((cg >> 5) << 4) + lr;
      const float bfv = e0[realcol], bav = e1[realcol];
      float cs = 0.0f;
      #pragma unroll
      for (int i = 0; i < 4; ++i) {
        const int rl = rbase + wr * 64 + i * 16 + kb * 4;
        #pragma unroll
        for (int r = 0; r < 4; ++r) {
          if (rl + r < 5096) {
            const float fv = acc[i][j][r] + bfv;
            const float gv = acc[i][j + 1][r] + bav;
            cs += sigmoidf_(gv) * fv;
          }
        }
      }
      cs += __shfl_xor(cs, 16);
      cs += __shfl_xor(cs, 32);
      if (l < 16) atomicAdd(&xf[(size_t)bseg * 512 + realcol], cs);
    }
  }
}

// --------------------------------------------------------------------------
// Flash PV (intra): out = E @ xp with E built on the fly from s,t.
// grid (2 ct of 128 cols, 2 rh, G); per block 2 row-tiles of 128.
// Epilogue: *dinv, elu(+bias), +h residual -> x2.
// --------------------------------------------------------------------------
__global__ __launch_bounds__(256) void pv_flash_k(
    const short* __restrict__ xpT, const float* __restrict__ sb,
    const float* __restrict__ tb, const float* __restrict__ dinv,
    const float* __restrict__ bias, const short* __restrict__ h,
    short* __restrict__ x2) {
  const int g = blockIdx.z;
  const int rh = blockIdx.y;
  const int ct = blockIdx.x;
  const int tid = threadIdx.x;
  const int w = tid >> 6, l = tid & 63;
  const int lr = l & 15, kb = l >> 4;
  const int wr = w >> 1, wc = w & 1;

  __shared__ short As[128][32];
  __shared__ short Bs[128][32];
  __shared__ float t_s[416];
  __shared__ float red[256];

  for (int i = tid; i < 416; i += 256)
    t_s[i] = (i < 392) ? tb[(size_t)g * 392 + i] : -1e30f;
  __syncthreads();
  float lm = -1e30f;
  for (int i = tid; i < 392; i += 256) lm = fmaxf(lm, t_s[i]);
  red[tid] = lm;
  __syncthreads();
  for (int off = 128; off; off >>= 1) {
    if (tid < off) red[tid] = fmaxf(red[tid], red[tid + off]);
    __syncthreads();
  }
  const float tmax = red[0];

  const int srow = w * 32 + (l >> 2);
  const int sso = (l & 3) * 8;
  const short* bg0 = xpT + ((size_t)g * 256 + ct * 128 + srow) * 448 + sso;
  const short* bg1 = bg0 + (size_t)16 * 448;
  const int bb = g / 13, rr = g % 13;

  for (int rt = 0; rt < 2; ++rt) {
    const int row0 = rh * 256 + rt * 128;
    const int ar0 = row0 + srow, ar1 = row0 + srow + 16;
    const bool v0 = ar0 < 392, v1 = ar1 < 392;
    const float sv0 = v0 ? sb[(size_t)g * 392 + ar0] : 0.0f;
    const float sv1 = v1 ? sb[(size_t)g * 392 + ar1] : 0.0f;
    const float lt0 = leakyf_(sv0 + tmax);
    const float lt1 = leakyf_(sv1 + tmax);

    f32x4 acc[4][4];
    #pragma unroll
    for (int i = 0; i < 4; ++i)
      #pragma unroll
      for (int j = 0; j < 4; ++j) acc[i][j] = fzero4();

    bf16x8 rb0 = *(const bf16x8*)bg0;
    bf16x8 rb1 = *(const bf16x8*)bg1;

    for (int kt = 0; kt < 13; ++kt) {
      __syncthreads();
      *(bf16x8*)&Bs[srow][sso] = rb0;
      *(bf16x8*)&Bs[srow + 16][sso] = rb1;
      {
        const int mb = kt * 32 + sso;
        bf16x8 e0v, e1v;
        #pragma unroll
        for (int i = 0; i < 8; ++i) {
          const float tm = t_s[mb + i];
          e0v[i] = v0 ? f2bf(__expf(leakyf_(sv0 + tm) - lt0)) : (short)0;
          e1v[i] = v1 ? f2bf(__expf(leakyf_(sv1 + tm) - lt1)) : (short)0;
        }
        *(bf16x8*)&As[srow][sso] = e0v;
        *(bf16x8*)&As[srow + 16][sso] = e1v;
      }
      if (kt + 1 < 13) {
        const int ko = (kt + 1) * 32;
        rb0 = *(const bf16x8*)(bg0 + ko);
        rb1 = *(const bf16x8*)(bg1 + ko);
      }
      __syncthreads();
      bf16x8 va[4], vb[4];
      #pragma unroll
      for (int i = 0; i < 4; ++i) va[i] = *(const bf16x8*)&As[wr * 64 + i * 16 + lr][kb * 8];
      #pragma unroll
      for (int j = 0; j < 4; ++j) vb[j] = *(const bf16x8*)&Bs[wc * 64 + j * 16 + lr][kb * 8];
      #pragma unroll
      for (int i = 0; i < 4; ++i)
        #pragma unroll
        for (int j = 0; j < 4; ++j) acc[i][j] = MFMA16x32(va[i], vb[j], acc[i][j]);
    }

    #pragma unroll
    for (int j = 0; j < 4; ++j) {
      const int col = ct * 128 + wc * 64 + j * 16 + lr;
      const float bv = bias[col];
      #pragma unroll
      for (int i = 0; i < 4; ++i) {
        const int rl = row0 + wr * 64 + i * 16 + kb * 4;
        #pragma unroll
        for (int r = 0; r < 4; ++r) {
          const int row = rl + r;
          if (row < 392) {
            const size_t grow = (size_t)g * 392 + row;
            const float o = acc[i][j][r] * dinv[grow];
            const float val = eluf_(o + bv) + bf2f(h[grow * 256 + col]);
            x2[((size_t)bb * 5120 + rr * 392 + row) * 256 + col] = f2bf(val);
          }
        }
      }
    }
  }
}

// --------------------------------------------------------------------------
// Intra softmax denominators: dinv[g][n] = 1/sum_m exp(leaky(s+t)-leaky(s+tmax)).
// --------------------------------------------------------------------------
__global__ __launch_bounds__(256) void denom_k(const float* __restrict__ sb,
    const float* __restrict__ tb, float* __restrict__ dinv) {
  const int g = blockIdx.x;
  const int tid = threadIdx.x;
  __shared__ float t_s[392];
  __shared__ float red[256];
  for (int i = tid; i < 392; i += 256) t_s[i] = tb[(size_t)g * 392 + i];
  __syncthreads();
  float lm = -1e30f;
  for (int i = tid; i < 392; i += 256) lm = fmaxf(lm, t_s[i]);
  red[tid] = lm;
  __syncthreads();
  for (int off = 128; off; off >>= 1) {
    if (tid < off) red[tid] = fmaxf(red[tid], red[tid + off]);
    __syncthreads();
  }
  const float tmax = red[0];
  for (int n = tid; n < 392; n += 256) {
    const float sv = sb[(size_t)g * 392 + n];
    const float lt = leakyf_(sv + tmax);
    float d0 = 0.0f, d1 = 0.0f;
    for (int m = 0; m < 392; m += 2) {
      d0 += __expf(leakyf_(sv + t_s[m]) - lt);
      d1 += __expf(leakyf_(sv + t_s[m + 1]) - lt);
    }
    dinv[(size_t)g * 392 + n] = 1.0f / (d0 + d1);
  }
}

// --------------------------------------------------------------------------
// Transpose xp[g][392][256] -> xpT[g][256][448] (cols 392..447 zero).
// --------------------------------------------------------------------------
__global__ __launch_bounds__(256) void transpose_k(const short* __restrict__ xp,
                                                   short* __restrict__ xpT) {
  const int m0 = blockIdx.x * 64;
  const int f0 = blockIdx.y * 64;
  const int g = blockIdx.z;
  const int tid = threadIdx.x;
  __shared__ short tile[64][66];
  const int c = tid & 63;
  const int r4 = tid >> 6;
  #pragma unroll
  for (int p = 0; p < 16; ++p) {
    const int row = p * 4 + r4;
    const int m = m0 + row;
    tile[row][c] = (m < 392) ? xp[((size_t)g * 392 + m) * 256 + f0 + c] : (short)0;
  }
  __syncthreads();
  #pragma unroll
  for (int p = 0; p < 16; ++p) {
    const int fr = p * 4 + r4;
    xpT[((size_t)g * 256 + f0 + fr) * 448 + m0 + c] = tile[c][fr];
  }
}

// --------------------------------------------------------------------------
// Graph feature sums of m (bf16 in, fp32 out).
// --------------------------------------------------------------------------
__global__ void sums_intra_k(const short* __restrict__ m, float* __restrict__ S) {
  const int g = blockIdx.x;
  const int f = threadIdx.x;
  const short* p = m + (size_t)g * 392 * 256 + f;
  float a0 = 0.0f, a1 = 0.0f, a2 = 0.0f, a3 = 0.0f;
  for (int c = 0; c < 392; c += 4) {
    a0 += bf2f(p[(size_t)(c + 0) * 256]);
    a1 += bf2f(p[(size_t)(c + 1) * 256]);
    a2 += bf2f(p[(size_t)(c + 2) * 256]);
    a3 += bf2f(p[(size_t)(c + 3) * 256]);
  }
  S[(size_t)g * 256 + f] = (a0 + a1) + (a2 + a3);
}

__global__ void sums_inter_k(const short* __restrict__ m, float* __restrict__ S) {
  const int g = blockIdx.x;
  const int b = g / 392, c = g % 392;
  const int f = threadIdx.x;
  const short* p = m + ((size_t)(b * 13) * 392 + c) * 256 + f;
  float acc = 0.0f;
  #pragma unroll
  for (int r = 0; r < 13; ++r) acc += bf2f(p[(size_t)r * 392 * 256]);
  S[(size_t)g * 256 + f] = acc;
}

// --------------------------------------------------------------------------
// h = 0.9*(S_g + m)/(n+1) + 0.1*m + x  (APPNP + residual), fused with
// attention scalars s = h.was, t = h.wan (32 threads per row, xor-reduce).
// Block covers 8 rows; thread = (row_local = tid>>5, f0 = (tid&31)*8).
// --------------------------------------------------------------------------
template <int INTRA>
__global__ void h_st_v(const short* __restrict__ nodes, const short* __restrict__ m,
                       const float* __restrict__ S, const float* __restrict__ was,
                       const float* __restrict__ wan, short* __restrict__ h,
                       float* __restrict__ sb, float* __restrict__ tb) {
  const int row = blockIdx.x * 8 + (threadIdx.x >> 5);
  const int f0 = (threadIdx.x & 31) * 8;
  int g;
  float inv;
  if constexpr (INTRA) { g = row / 392; inv = 1.0f / 393.0f; }
  else { const int b = row / 5096; g = b * 392 + row % 392; inv = 1.0f / 14.0f; }
  const size_t e0 = (size_t)row * 256 + f0;
  const bf16x8 mv8 = *(const bf16x8*)(m + e0);
  const bf16x8 nv8 = *(const bf16x8*)(nodes + e0);
  const float* Sp = S + (size_t)g * 256 + f0;
  bf16x8 o;
  float s = 0.0f, t = 0.0f;
  #pragma unroll
  for (int i = 0; i < 8; ++i) {
    const float mv = bf2f(mv8[i]);
    const float hv = 0.9f * (Sp[i] + mv) * inv + 0.1f * mv + bf2f(nv8[i]);
    o[i] = f2bf(hv);
    s = fmaf(hv, was[f0 + i], s);
    t = fmaf(hv, wan[f0 + i], t);
  }
  *(bf16x8*)(h + e0) = o;
  #pragma unroll
  for (int off = 16; off; off >>= 1) {
    s += __shfl_xor(s, off, 32);
    t += __shfl_xor(t, off, 32);
  }
  if ((threadIdx.x & 31) == 0) { sb[row] = s; tb[row] = t; }
}

// --------------------------------------------------------------------------
// Inter attention: 13-node graphs, one block per (b,c).
// --------------------------------------------------------------------------
__global__ __launch_bounds__(256) void attn_inter_k(const short* __restrict__ xp,
    const float* __restrict__ sb, const float* __restrict__ tb,
    const short* __restrict__ h, const float* __restrict__ bias,
    short* __restrict__ x2, int B) {
  const int g = blockIdx.x;
  const int b = g / 392, c = g % 392;
  const int tid = threadIdx.x;
  __shared__ float xps[13][256];
  __shared__ float e_s[13][14];
  __shared__ float sv[13], tv[13], denom[13];
  __shared__ float tmax_s;
  for (int lin = tid; lin < 13 * 256; lin += 256) {
    const int r = lin >> 8, f = lin & 255;
    xps[r][f] = bf2f(xp[((size_t)(b * 13 + r) * 392 + c) * 256 + f]);
  }
  if (tid < 13) {
    const size_t row = (size_t)(b * 13 + tid) * 392 + c;
    sv[tid] = sb[row];
    tv[tid] = tb[row];
  }
  __syncthreads();
  if (tid == 0) {
    float mx = tv[0];
    for (int r = 1; r < 13; ++r) mx = fmaxf(mx, tv[r]);
    tmax_s = mx;
  }
  __syncthreads();
  if (tid < 169) {
    const int n = tid / 13, mm = tid % 13;
    e_s[n][mm] = expf(leakyf_(sv[n] + tv[mm]) - leakyf_(sv[n] + tmax_s));
  }
  __syncthreads();
  if (tid < 13) {
    float d = 0.0f;
    for (int mm = 0; mm < 13; ++mm) d += e_s[tid][mm];
    denom[tid] = d;
  }
  __syncthreads();
  const int f = tid;
  for (int n = 0; n < 13; ++n) {
    float acc = 0.0f;
    #pragma unroll
    for (int mm = 0; mm < 13; ++mm) acc = fmaf(e_s[n][mm], xps[mm][f], acc);
    const float o = acc / denom[n];
    const size_t hbase = ((size_t)(b * 13 + n) * 392 + c) * 256 + f;
    x2[(((size_t)(B + b)) * 5120 + (size_t)n * 392 + c) * 256 + f] =
        f2bf(eluf_(o + bias[f]) + bf2f(h[hbase]));
  }
}

// --------------------------------------------------------------------------
// Head: BN + dense(512->200) + softmax.
// --------------------------------------------------------------------------
__global__ __launch_bounds__(256) void head_k(const float* __restrict__ xf,
    const float* __restrict__ gamma, const float* __restrict__ beta,
    const float* __restrict__ mean, const float* __restrict__ var,
    const float* __restrict__ Wd, const float* __restrict__ bd,
    float* __restrict__ out) {
  const int b = blockIdx.x;
  const int tid = threadIdx.x;
  __shared__ float xn[512];
  __shared__ float red[256];
  for (int i = tid; i < 512; i += 256) {
    const float v = xf[(size_t)b * 512 + i];
    xn[i] = (v - mean[i]) / sqrtf(var[i] + 1e-3f) * gamma[i] + beta[i];
  }
  __syncthreads();
  float logit = -1e30f;
  if (tid < 200) {
    float acc = bd[tid];
    for (int i = 0; i < 512; ++i) acc = fmaf(xn[i], Wd[(size_t)i * 200 + tid], acc);
    logit = acc;
  }
  red[tid] = logit;
  __syncthreads();
  for (int off = 128; off; off >>= 1) {
    if (tid < off) red[tid] = fmaxf(red[tid], red[tid + off]);
    __syncthreads();
  }
  const float mx = red[0];
  __syncthreads();
  const float e = (tid < 200) ? expf(logit - mx) : 0.0f;
  red[tid] = e;
  __syncthreads();
  for (int off = 128; off; off >>= 1) {
    if (tid < off) red[tid] += red[tid + off];
    __syncthreads();
  }
  const float inv = 1.0f / red[0];
  if (tid < 200) out[(size_t)b * 200 + tid] = e * inv;
}

// ---------------------------------------------------------------------------
extern "C" void kernel_launch(void* const* d_in, const int* in_sizes, int n_in,
                              void* d_out, int out_size, void* d_ws, size_t ws_size,
                              hipStream_t stream) {
  (void)n_in; (void)out_size; (void)ws_size;
  const float* base    = (const float*)d_in[0];
  const float* appnp_w = (const float*)d_in[1];
  const float* appnp_b = (const float*)d_in[2];
  const float* gat_k   = (const float*)d_in[3];
  const float* gat_as  = (const float*)d_in[4];
  const float* gat_an  = (const float*)d_in[5];
  const float* gat_b   = (const float*)d_in[6];
  const float* pf_w    = (const float*)d_in[7];
  const float* pf_b    = (const float*)d_in[8];
  const float* pa_w    = (const float*)d_in[9];
  const float* pa_b    = (const float*)d_in[10];
  const float* bn_g    = (const float*)d_in[11];
  const float* bn_be   = (const float*)d_in[12];
  const float* bn_mu   = (const float*)d_in[13];
  const float* bn_va   = (const float*)d_in[14];
  const float* dw      = (const float*)d_in[15];
  const float* db      = (const float*)d_in[16];
  float* out = (float*)d_out;

  const int B = in_sizes[0] / (49 * 2048);   // 8
  const int G = B * 13;                      // 104 intra graphs
  const int R = G * 392;                     // 40768 node rows per branch
  const int Mt = (R + 127) / 128;            // 319 row tiles
  const int Rpad = Mt * 128;                 // 40832 (A-panel slack)
  const int MP = 2 * B * 5120;               // padded pool rows (81920)

  char* ws = (char*)d_ws;
  size_t off = 0;
  auto alloc = [&](size_t bytes) -> void* {
    void* p = (void*)(ws + off);
    off += (bytes + 255) & ~(size_t)255;
    return p;
  };
  float* wtab   = (float*)alloc((size_t)13 * 2 * 49 * 4);
  short* aWhi   = (short*)alloc((size_t)256 * 256 * 2);
  short* gkhi   = (short*)alloc((size_t)256 * 256 * 2);
  short* pwcomb = (short*)alloc((size_t)1024 * 256 * 2);
  float* was    = (float*)alloc((size_t)256 * 4);
  float* wan    = (float*)alloc((size_t)256 * 4);
  short* nodes  = (short*)alloc((size_t)Rpad * 256 * 2);
  short* mbuf   = (short*)alloc((size_t)R * 256 * 2);
  short* hbuf   = (short*)alloc((size_t)Rpad * 256 * 2);
  short* xpbuf  = (short*)alloc((size_t)R * 256 * 2);
  short* xpT    = (short*)alloc((size_t)G * 256 * 448 * 2);
  short* x2buf  = (short*)alloc((size_t)MP * 256 * 2);
  float* Sintra = (float*)alloc((size_t)G * 256 * 4);
  float* Sinter = (float*)alloc((size_t)B * 392 * 256 * 4);
  float* sbuf   = (float*)alloc((size_t)R * 4);
  float* tbuf   = (float*)alloc((size_t)R * 4);
  float* dinv   = (float*)alloc((size_t)R * 4);
  float* xf     = (float*)alloc((size_t)B * 512 * 4);

  hipMemsetAsync(xf, 0, (size_t)B * 512 * 4, stream);
  wtab_k<<<1, 256, 0, stream>>>(wtab);
  wcvt_k<<<(256 * 256 + 255) / 256, 256, 0, stream>>>(appnp_w, aWhi, 256, 256);
  wcvt_k<<<(256 * 256 + 255) / 256, 256, 0, stream>>>(gat_k, gkhi, 256, 256);
  wcvt_pool_k<<<1024, 256, 0, stream>>>(pf_w, pa_w, pwcomb);
  wvec_k<<<64, 256, 0, stream>>>(gat_k, gat_as, gat_an, was, wan);
  nodes_k<<<B * 13 * 8, 256, 0, stream>>>(base, wtab, nodes);

  // m = sigmoid(nodes @ appnp_w + b)  (shared by both branches)
  gemm_t<EP_SIG><<<dim3(Mt, 2), 256, 0, stream>>>(nodes, aWhi, 256, 8, R,
      appnp_b, nullptr, mbuf, nullptr);
  sums_intra_k<<<G, 256, 0, stream>>>(mbuf, Sintra);
  sums_inter_k<<<B * 392, 256, 0, stream>>>(mbuf, Sinter);

  // ---- intra branch ----
  h_st_v<1><<<R / 8, 256, 0, stream>>>(nodes, mbuf, Sintra, was, wan, hbuf, sbuf, tbuf);
  gemm_t<EP_PLAIN><<<dim3(Mt, 2), 256, 0, stream>>>(hbuf, gkhi, 256, 8, R,
      nullptr, nullptr, xpbuf, nullptr);
  transpose_k<<<dim3(7, 4, G), 256, 0, stream>>>(xpbuf, xpT);
  denom_k<<<G, 256, 0, stream>>>(sbuf, tbuf, dinv);
  pv_flash_k<<<dim3(2, 2, G), 256, 0, stream>>>(xpT, sbuf, tbuf, dinv, gat_b,
                                                hbuf, x2buf);

  // ---- inter branch ----
  h_st_v<0><<<R / 8, 256, 0, stream>>>(nodes, mbuf, Sinter, was, wan, hbuf, sbuf, tbuf);
  gemm_t<EP_PLAIN><<<dim3(Mt, 2), 256, 0, stream>>>(hbuf, gkhi, 256, 8, R,
      nullptr, nullptr, xpbuf, nullptr);
  attn_inter_k<<<B * 392, 256, 0, stream>>>(xpbuf, sbuf, tbuf, hbuf, gat_b, x2buf, B);

  // ---- pool + head ----
  gemm_t<EP_POOL><<<5120, 256, 0, stream>>>(x2buf, pwcomb, 256, 8, 0,
      pf_b, pa_b, nullptr, xf);
  head_k<<<B, 256, 0, stream>>>(xf, bn_g, bn_be, bn_mu, bn_va, dw, db, out);
}